// Round 4
// baseline (581.671 us; speedup 1.0000x reference)
//
#include <hip/hip_runtime.h>
#include <math.h>

// Problem constants (B=16, H=W=56, C=512, window=7)
#define NTOK_PER_B 3136
#define NBATCH 16
#define M_TOK (NTOK_PER_B * NBATCH)   // 50176
#define CDIM 512
#define NWIN 448                      // 3136 / 7
#define SCALE 0.04419417382415922f    // 512^-0.5

typedef _Float16 half8 __attribute__((ext_vector_type(8)));
typedef float f32x4 __attribute__((ext_vector_type(4)));

#define GLOAD16(g, l) __builtin_amdgcn_global_load_lds( \
    (const __attribute__((address_space(1))) void*)(g),  \
    (__attribute__((address_space(3))) void*)(l), 16, 0, 0)

__device__ __forceinline__ float wave_sum64(float s) {
    #pragma unroll
    for (int o = 32; o >= 1; o >>= 1) s += __shfl_xor(s, o, 64);
    return s;
}

// ---------------------------------------------------------------------------
// x (fp32) -> fp16, 8 elems/thread
// ---------------------------------------------------------------------------
__global__ __launch_bounds__(256) void cvt_f32_f16(
    const float* __restrict__ x, _Float16* __restrict__ y)
{
    const size_t i = ((size_t)blockIdx.x * 256 + threadIdx.x) * 8;
    const float4 a = *(const float4*)(x + i);
    const float4 b = *(const float4*)(x + i + 4);
    half8 o;
    o[0] = (_Float16)a.x; o[1] = (_Float16)a.y; o[2] = (_Float16)a.z; o[3] = (_Float16)a.w;
    o[4] = (_Float16)b.x; o[5] = (_Float16)b.y; o[6] = (_Float16)b.z; o[7] = (_Float16)b.w;
    *(half8*)(y + i) = o;
}

// ---------------------------------------------------------------------------
// W [K=512][N=512] fp32 -> Wt [N][K] fp16 (transposed), 3 matrices via z
// ---------------------------------------------------------------------------
__global__ __launch_bounds__(256) void cvt_w_t(
    const float* __restrict__ w0, const float* __restrict__ w1,
    const float* __restrict__ w2, _Float16* __restrict__ wt)
{
    const float* w = (blockIdx.z == 0) ? w0 : ((blockIdx.z == 1) ? w1 : w2);
    _Float16* o = wt + (size_t)blockIdx.z * CDIM * CDIM;
    __shared__ float tile[32][33];
    const int tx = threadIdx.x & 31;
    const int ty = threadIdx.x >> 5;          // 0..7
    const int k0 = blockIdx.x * 32;
    const int n0 = blockIdx.y * 32;
    #pragma unroll
    for (int r = 0; r < 32; r += 8)
        tile[ty + r][tx] = w[(size_t)(k0 + ty + r) * CDIM + n0 + tx];
    __syncthreads();
    #pragma unroll
    for (int r = 0; r < 32; r += 8)
        o[(size_t)(n0 + ty + r) * CDIM + k0 + tx] = (_Float16)tile[tx][ty + r];
}

// ---------------------------------------------------------------------------
// Fused QKV GEMM: for z in {q,k,v}: out[z] = xh @ Wt[z]^T + bias[z].
// One A-tile stage feeds 3x16 MFMAs. 128x128 tile, BK=32, 4 waves (2x2),
// 4x4 16x16x32 frags per z. grid = (392, 4).
// ---------------------------------------------------------------------------
__global__ __launch_bounds__(256) void qkv_gemm_f16_fused(
    const _Float16* __restrict__ A,
    const _Float16* __restrict__ Wt,
    const float* __restrict__ b0, const float* __restrict__ b1,
    const float* __restrict__ b2,
    _Float16* __restrict__ out)
{
    __shared__ _Float16 As[128 * 32];        // [row][k]
    __shared__ _Float16 Bs[3][128 * 32];     // [z][n][k]

    const int t    = threadIdx.x;
    const int lane = t & 63;
    const int wid  = t >> 6;
    const int wrow = (wid >> 1) * 64;
    const int wcol = (wid & 1) * 64;
    const int row0 = blockIdx.x * 128;
    const int col0 = blockIdx.y * 128;

    // chunk c (0..511) -> LDS halfs c*8; row c>>2, k-slot (c&3)*8
    const _Float16* aSrc0 = A + (size_t)(row0 + (t >> 2)) * CDIM + (t & 3) * 8;
    const _Float16* aSrc1 = aSrc0 + (size_t)64 * CDIM;
    const size_t bRow = (size_t)(col0 + (t >> 2)) * CDIM + (t & 3) * 8;
    _Float16* aDst0 = As + t * 8;
    _Float16* aDst1 = As + (t + 256) * 8;

    f32x4 acc[3][4][4];
    #pragma unroll
    for (int z = 0; z < 3; ++z)
        #pragma unroll
        for (int m = 0; m < 4; ++m)
            #pragma unroll
            for (int n = 0; n < 4; ++n)
                acc[z][m][n] = (f32x4){0.f, 0.f, 0.f, 0.f};

    const int fr  = lane & 15;
    const int q8o = (lane >> 4) * 8;

    for (int k0 = 0; k0 < CDIM; k0 += 32) {
        GLOAD16(aSrc0 + k0, aDst0);
        GLOAD16(aSrc1 + k0, aDst1);
        #pragma unroll
        for (int z = 0; z < 3; ++z) {
            const _Float16* bs = Wt + (size_t)z * CDIM * CDIM + bRow + k0;
            GLOAD16(bs, &Bs[z][t * 8]);
            GLOAD16(bs + (size_t)64 * CDIM, &Bs[z][(t + 256) * 8]);
        }
        __syncthreads();   // drains vmcnt: LDS tiles ready

        half8 af[4];
        #pragma unroll
        for (int m = 0; m < 4; ++m)
            af[m] = *(const half8*)(As + (wrow + m * 16 + fr) * 32 + q8o);
        #pragma unroll
        for (int z = 0; z < 3; ++z) {
            half8 bf[4];
            #pragma unroll
            for (int n = 0; n < 4; ++n)
                bf[n] = *(const half8*)(&Bs[z][0] + (wcol + n * 16 + fr) * 32 + q8o);
            #pragma unroll
            for (int m = 0; m < 4; ++m)
                #pragma unroll
                for (int n = 0; n < 4; ++n)
                    acc[z][m][n] = __builtin_amdgcn_mfma_f32_16x16x32_f16(
                        af[m], bf[n], acc[z][m][n], 0, 0, 0);
        }
        __syncthreads();   // LDS reads done before next overwrite
    }

    // epilogue: bias + fp16 store. C/D: col=lane&15, row=(lane>>4)*4+reg
    const int rq = (lane >> 4) * 4;
    #pragma unroll
    for (int z = 0; z < 3; ++z) {
        const float* bias = (z == 0) ? b0 : ((z == 1) ? b1 : b2);
        _Float16* O = out + (size_t)z * (size_t)M_TOK * CDIM;
        float bval[4];
        #pragma unroll
        for (int n = 0; n < 4; ++n)
            bval[n] = bias[col0 + wcol + n * 16 + fr];
        #pragma unroll
        for (int m = 0; m < 4; ++m) {
            #pragma unroll
            for (int r = 0; r < 4; ++r) {
                const int row = row0 + wrow + m * 16 + rq + r;
                _Float16* op = O + (size_t)row * CDIM + col0 + wcol + fr;
                #pragma unroll
                for (int n = 0; n < 4; ++n)
                    op[n * 16] = (_Float16)(acc[z][m][n][r] + bval[n]);
            }
        }
    }
}

// ---------------------------------------------------------------------------
// Local attention, k-norm fused. One block per (batch, window), 7 waves =
// 1 wave per query row. Lane owns 8 channels. Norms computed once per block
// (wave i reduces keys 2i, 2i+1). self=-5e4, causal/pad=-FLT_MAX.
// ---------------------------------------------------------------------------
__global__ __launch_bounds__(448) void local_attn_f16(
    const _Float16* __restrict__ q,
    const _Float16* __restrict__ k,
    const _Float16* __restrict__ v,
    float* __restrict__ out)
{
    const int blk   = blockIdx.x;
    const int batch = blk / NWIN;
    const int win   = blk % NWIN;
    const int i     = threadIdx.x >> 6;    // query row 0..6
    const int lane  = threadIdx.x & 63;
    const int c     = lane * 8;

    __shared__ float norms_s[14];

    const long long tok0 = (long long)batch * NTOK_PER_B + (long long)win * 7;

    const half8 q8 = *(const half8*)(q + (tok0 + i) * CDIM + c);

    // load K rows (guarded: window 0 has no previous window)
    half8 kreg[14];
    #pragma unroll
    for (int j = 0; j < 14; ++j) {
        const bool valid = (win > 0) || (j >= 7);
        if (valid) kreg[j] = *(const half8*)(k + (tok0 - 7 + j) * CDIM + c);
        else       kreg[j] = (half8)(_Float16)0.f;
    }

    // squared-norm partials for all j (cheap), then wave i reduces j=2i,2i+1
    float np[14];
    #pragma unroll
    for (int j = 0; j < 14; ++j) {
        float s = 0.f;
        #pragma unroll
        for (int e = 0; e < 8; ++e) {
            const float f = (float)kreg[j][e];
            s = fmaf(f, f, s);
        }
        np[j] = s;
    }
    // static-index selection of this wave's two norms (rule #20: no np[2*i])
    float na = 0.f, nb = 0.f;
    #pragma unroll
    for (int j = 0; j < 14; ++j) {
        if (j == 2 * i)     na = np[j];
        if (j == 2 * i + 1) nb = np[j];
    }
    na = wave_sum64(na);
    nb = wave_sum64(nb);
    if (lane == 0) {
        norms_s[2 * i]     = sqrtf(na);
        norms_s[2 * i + 1] = sqrtf(nb);
    }

    // dot partials + wave reduce
    float dots[14];
    #pragma unroll
    for (int j = 0; j < 14; ++j) {
        float d = 0.f;
        #pragma unroll
        for (int e = 0; e < 8; ++e)
            d = fmaf((float)q8[e], (float)kreg[j][e], d);
        dots[j] = wave_sum64(d);
    }
    __syncthreads();   // norms_s ready

    // mask + softmax (redundant across lanes, in-register)
    float sc[14];
    #pragma unroll
    for (int j = 0; j < 14; ++j) {
        const bool valid = (win > 0) || (j >= 7);
        if (j > i + 7 || !valid)  sc[j] = -3.402823466e38f;  // causal / pad
        else if (j == i + 7)      sc[j] = -5e4f;              // shared-qk self
        else                      sc[j] = dots[j] * SCALE / fmaxf(norms_s[j], 1e-12f);
    }
    float m = sc[0];
    #pragma unroll
    for (int j = 1; j < 14; ++j) m = fmaxf(m, sc[j]);
    float sum = 0.f;
    #pragma unroll
    for (int j = 0; j < 14; ++j) {
        sc[j] = __expf(sc[j] - m);
        sum += sc[j];
    }
    const float inv = 1.f / sum;

    // PV
    float o[8];
    #pragma unroll
    for (int e = 0; e < 8; ++e) o[e] = 0.f;
    #pragma unroll
    for (int j = 0; j < 14; ++j) {
        const bool valid = (win > 0) || (j >= 7);
        if (valid) {
            const half8 v8 = *(const half8*)(v + (tok0 - 7 + j) * CDIM + c);
            const float a = sc[j] * inv;
            #pragma unroll
            for (int e = 0; e < 8; ++e)
                o[e] = fmaf(a, (float)v8[e], o[e]);
        }
    }

    float* op = out + (tok0 + i) * CDIM + c;
    *(float4*)(op)     = make_float4(o[0], o[1], o[2], o[3]);
    *(float4*)(op + 4) = make_float4(o[4], o[5], o[6], o[7]);
}

// ---------------------------------------------------------------------------
extern "C" void kernel_launch(void* const* d_in, const int* in_sizes, int n_in,
                              void* d_out, int out_size, void* d_ws, size_t ws_size,
                              hipStream_t stream)
{
    const float* x  = (const float*)d_in[0];
    const float* wq = (const float*)d_in[1];
    const float* bq = (const float*)d_in[2];
    const float* wk = (const float*)d_in[3];
    const float* bk = (const float*)d_in[4];
    const float* wv = (const float*)d_in[5];
    const float* bv = (const float*)d_in[6];
    float* out = (float*)d_out;

    char* ws = (char*)d_ws;
    const size_t XH_BYTES = (size_t)M_TOK * CDIM * sizeof(_Float16);   // 51.4 MB
    const size_t WT_BYTES = (size_t)3 * CDIM * CDIM * sizeof(_Float16);
    _Float16* xh  = (_Float16*)ws;
    _Float16* wt  = (_Float16*)(ws + XH_BYTES);
    _Float16* qkv = (_Float16*)(ws + XH_BYTES + WT_BYTES);
    _Float16* qh = qkv;
    _Float16* kh = qkv + (size_t)M_TOK * CDIM;
    _Float16* vh = kh  + (size_t)M_TOK * CDIM;

    cvt_f32_f16<<<12544, 256, 0, stream>>>(x, xh);
    cvt_w_t<<<dim3(16, 16, 3), 256, 0, stream>>>(wq, wk, wv, wt);
    qkv_gemm_f16_fused<<<dim3(M_TOK / 128, CDIM / 128), 256, 0, stream>>>(
        xh, wt, bq, bk, bv, qkv);
    local_attn_f16<<<NBATCH * NWIN, 448, 0, stream>>>(qh, kh, vh, out);
}

// Round 5
// 409.166 us; speedup vs baseline: 1.4216x; 1.4216x over previous
//
#include <hip/hip_runtime.h>
#include <math.h>

// Problem constants (B=16, H=W=56, C=512, window=7)
#define NTOK_PER_B 3136
#define NBATCH 16
#define M_TOK (NTOK_PER_B * NBATCH)   // 50176
#define CDIM 512
#define NWIN 448                      // 3136 / 7
#define SCALE 0.04419417382415922f    // 512^-0.5

typedef _Float16 half8 __attribute__((ext_vector_type(8)));
typedef float f32x4 __attribute__((ext_vector_type(4)));

#define GLOAD16(g, l) __builtin_amdgcn_global_load_lds( \
    (const __attribute__((address_space(1))) void*)(g),  \
    (__attribute__((address_space(3))) void*)(l), 16, 0, 0)

__device__ __forceinline__ float wave_sum64(float s) {
    #pragma unroll
    for (int o = 32; o >= 1; o >>= 1) s += __shfl_xor(s, o, 64);
    return s;
}

// ---------------------------------------------------------------------------
// x (fp32) -> fp16, 8 elems/thread
// ---------------------------------------------------------------------------
__global__ __launch_bounds__(256) void cvt_f32_f16(
    const float* __restrict__ x, _Float16* __restrict__ y)
{
    const size_t i = ((size_t)blockIdx.x * 256 + threadIdx.x) * 8;
    const float4 a = *(const float4*)(x + i);
    const float4 b = *(const float4*)(x + i + 4);
    half8 o;
    o[0] = (_Float16)a.x; o[1] = (_Float16)a.y; o[2] = (_Float16)a.z; o[3] = (_Float16)a.w;
    o[4] = (_Float16)b.x; o[5] = (_Float16)b.y; o[6] = (_Float16)b.z; o[7] = (_Float16)b.w;
    *(half8*)(y + i) = o;
}

// ---------------------------------------------------------------------------
// W [K=512][N=512] fp32 -> Wt [N][K] fp16 (transposed), 3 matrices via z
// ---------------------------------------------------------------------------
__global__ __launch_bounds__(256) void cvt_w_t(
    const float* __restrict__ w0, const float* __restrict__ w1,
    const float* __restrict__ w2, _Float16* __restrict__ wt)
{
    const float* w = (blockIdx.z == 0) ? w0 : ((blockIdx.z == 1) ? w1 : w2);
    _Float16* o = wt + (size_t)blockIdx.z * CDIM * CDIM;
    __shared__ float tile[32][33];
    const int tx = threadIdx.x & 31;
    const int ty = threadIdx.x >> 5;          // 0..7
    const int k0 = blockIdx.x * 32;
    const int n0 = blockIdx.y * 32;
    #pragma unroll
    for (int r = 0; r < 32; r += 8)
        tile[ty + r][tx] = w[(size_t)(k0 + ty + r) * CDIM + n0 + tx];
    __syncthreads();
    #pragma unroll
    for (int r = 0; r < 32; r += 8)
        o[(size_t)(n0 + ty + r) * CDIM + k0 + tx] = (_Float16)tile[tx][ty + r];
}

// ---------------------------------------------------------------------------
// GEMM: out[z][M,512] = xh[M,512] @ Wt[z]^T + bias[z]  (fp16 in, fp32 acc,
// fp16 out). 128x128 tile, BK=32, 4 waves (2x2), 4x4 16x16x32 MFMA frags.
// 2-phase double-buffered K-loop: stage tile t+1 BEFORE computing tile t,
// single __syncthreads per K-step (vmcnt+lgkm drain happens after MFMAs).
// grid = (4 cols, 392 rows, 3 z) -- col fastest so A row-tile siblings are
// launch-adjacent (L2/L3 A-reuse).
// ---------------------------------------------------------------------------
__global__ __launch_bounds__(256) void qkv_gemm_f16(
    const _Float16* __restrict__ A,
    const _Float16* __restrict__ Wt,
    const float* __restrict__ b0, const float* __restrict__ b1,
    const float* __restrict__ b2,
    _Float16* __restrict__ out)
{
    const int z = blockIdx.z;
    const _Float16* W = Wt + (size_t)z * CDIM * CDIM;
    const float* bias = (z == 0) ? b0 : ((z == 1) ? b1 : b2);
    _Float16* O = out + (size_t)z * (size_t)M_TOK * CDIM;

    __shared__ _Float16 As[2][128 * 32];   // [buf][row][k]
    __shared__ _Float16 Bs[2][128 * 32];   // [buf][n][k]

    const int t    = threadIdx.x;
    const int lane = t & 63;
    const int wid  = t >> 6;
    const int wrow = (wid >> 1) * 64;
    const int wcol = (wid & 1) * 64;
    const int row0 = blockIdx.y * 128;
    const int col0 = blockIdx.x * 128;

    // staging: chunk c (0..511) -> LDS halfs c*8; row c>>2, k-slot (c&3)*8
    const _Float16* aSrc0 = A + (size_t)(row0 + (t >> 2)) * CDIM + (t & 3) * 8;
    const _Float16* aSrc1 = aSrc0 + (size_t)64 * CDIM;
    const _Float16* bSrc0 = W + (size_t)(col0 + (t >> 2)) * CDIM + (t & 3) * 8;
    const _Float16* bSrc1 = bSrc0 + (size_t)64 * CDIM;

    f32x4 acc[4][4];
    #pragma unroll
    for (int m = 0; m < 4; ++m)
        #pragma unroll
        for (int n = 0; n < 4; ++n)
            acc[m][n] = (f32x4){0.f, 0.f, 0.f, 0.f};

    const int fr  = lane & 15;
    const int q8o = (lane >> 4) * 8;

#define STAGE(buf, kofs)                                          \
    do {                                                          \
        GLOAD16(aSrc0 + (kofs), &As[buf][t * 8]);                 \
        GLOAD16(aSrc1 + (kofs), &As[buf][(t + 256) * 8]);         \
        GLOAD16(bSrc0 + (kofs), &Bs[buf][t * 8]);                 \
        GLOAD16(bSrc1 + (kofs), &Bs[buf][(t + 256) * 8]);         \
    } while (0)

#define COMPUTE(buf)                                                        \
    do {                                                                    \
        half8 af[4], bf[4];                                                 \
        _Pragma("unroll")                                                   \
        for (int m = 0; m < 4; ++m)                                         \
            af[m] = *(const half8*)(&As[buf][(wrow + m * 16 + fr) * 32 + q8o]); \
        _Pragma("unroll")                                                   \
        for (int n = 0; n < 4; ++n)                                         \
            bf[n] = *(const half8*)(&Bs[buf][(wcol + n * 16 + fr) * 32 + q8o]); \
        _Pragma("unroll")                                                   \
        for (int m = 0; m < 4; ++m)                                         \
            _Pragma("unroll")                                               \
            for (int n = 0; n < 4; ++n)                                     \
                acc[m][n] = __builtin_amdgcn_mfma_f32_16x16x32_f16(         \
                    af[m], bf[n], acc[m][n], 0, 0, 0);                      \
    } while (0)

    // prologue: fill buf 0
    STAGE(0, 0);
    __syncthreads();

    int cur = 0;
    #pragma unroll 1
    for (int ks = 0; ks < 15; ++ks) {
        STAGE(cur ^ 1, (ks + 1) * 32);  // issue next tile's loads first
        COMPUTE(cur);                    // compute hides stage latency
        __syncthreads();                 // drain vmcnt/lgkm + barrier
        cur ^= 1;
    }
    COMPUTE(cur);                        // last tile, no stage, no barrier

    // epilogue: bias + fp16 store. C/D: col=lane&15, row=(lane>>4)*4+reg
    const int rq = (lane >> 4) * 4;
    float bval[4];
    #pragma unroll
    for (int n = 0; n < 4; ++n)
        bval[n] = bias[col0 + wcol + n * 16 + fr];
    #pragma unroll
    for (int m = 0; m < 4; ++m) {
        #pragma unroll
        for (int r = 0; r < 4; ++r) {
            const int row = row0 + wrow + m * 16 + rq + r;
            _Float16* op = O + (size_t)row * CDIM + col0 + wcol + fr;
            #pragma unroll
            for (int n = 0; n < 4; ++n)
                op[n * 16] = (_Float16)(acc[m][n][r] + bval[n]);
        }
    }
#undef STAGE
#undef COMPUTE
}

// ---------------------------------------------------------------------------
// k row L2-normalization in-place (fp16), one wave per token
// ---------------------------------------------------------------------------
__global__ __launch_bounds__(256) void knorm_f16(_Float16* __restrict__ k)
{
    const int tok  = blockIdx.x * 4 + (threadIdx.x >> 6);
    const int lane = threadIdx.x & 63;
    _Float16* p = k + (size_t)tok * CDIM + lane * 8;
    half8 v = *(const half8*)p;
    float s = 0.f;
    #pragma unroll
    for (int e = 0; e < 8; ++e) {
        const float f = (float)v[e];
        s = fmaf(f, f, s);
    }
    s = wave_sum64(s);
    const float scale = 1.f / fmaxf(sqrtf(s), 1e-12f);
    #pragma unroll
    for (int e = 0; e < 8; ++e)
        v[e] = (_Float16)((float)v[e] * scale);
    *(half8*)p = v;
}

// ---------------------------------------------------------------------------
// Local attention (R2-measured structure): one block per (batch, window),
// 7 waves = 1 wave per query row. Lane owns 8 channels, k loads inline
// (keeps VGPR below the 64 cliff). k pre-normalized by knorm_f16.
// self=-5e4, causal/pad=-FLT_MAX.
// ---------------------------------------------------------------------------
__global__ __launch_bounds__(448) void local_attn_f16(
    const _Float16* __restrict__ q,
    const _Float16* __restrict__ k,
    const _Float16* __restrict__ v,
    float* __restrict__ out)
{
    const int blk   = blockIdx.x;
    const int batch = blk / NWIN;
    const int win   = blk % NWIN;
    const int i     = threadIdx.x >> 6;    // query row 0..6
    const int lane  = threadIdx.x & 63;
    const int c     = lane * 8;

    const long long tok0 = (long long)batch * NTOK_PER_B + (long long)win * 7;

    const half8 q8 = *(const half8*)(q + (tok0 + i) * CDIM + c);

    float dots[14];
    #pragma unroll
    for (int j = 0; j < 14; ++j) {
        const bool valid = (win > 0) || (j >= 7);
        float d = 0.f;
        if (valid) {
            const half8 k8 = *(const half8*)(k + (tok0 - 7 + j) * CDIM + c);
            #pragma unroll
            for (int e = 0; e < 8; ++e)
                d = fmaf((float)q8[e], (float)k8[e], d);
        }
        dots[j] = wave_sum64(d);
    }

    // mask + softmax (in-register, redundant across lanes)
    float sc[14];
    #pragma unroll
    for (int j = 0; j < 14; ++j) {
        const bool valid = (win > 0) || (j >= 7);
        if (j > i + 7 || !valid)  sc[j] = -3.402823466e38f;  // causal / pad
        else if (j == i + 7)      sc[j] = -5e4f;              // shared-qk self
        else                      sc[j] = dots[j] * SCALE;
    }
    float m = sc[0];
    #pragma unroll
    for (int j = 1; j < 14; ++j) m = fmaxf(m, sc[j]);
    float sum = 0.f;
    #pragma unroll
    for (int j = 0; j < 14; ++j) {
        sc[j] = __expf(sc[j] - m);
        sum += sc[j];
    }
    const float inv = 1.f / sum;

    // PV
    float o[8];
    #pragma unroll
    for (int e = 0; e < 8; ++e) o[e] = 0.f;
    #pragma unroll
    for (int j = 0; j < 14; ++j) {
        const bool valid = (win > 0) || (j >= 7);
        if (valid) {
            const half8 v8 = *(const half8*)(v + (tok0 - 7 + j) * CDIM + c);
            const float a = sc[j] * inv;
            #pragma unroll
            for (int e = 0; e < 8; ++e)
                o[e] = fmaf(a, (float)v8[e], o[e]);
        }
    }

    float* op = out + (tok0 + i) * CDIM + c;
    *(float4*)(op)     = make_float4(o[0], o[1], o[2], o[3]);
    *(float4*)(op + 4) = make_float4(o[4], o[5], o[6], o[7]);
}

// ---------------------------------------------------------------------------
extern "C" void kernel_launch(void* const* d_in, const int* in_sizes, int n_in,
                              void* d_out, int out_size, void* d_ws, size_t ws_size,
                              hipStream_t stream)
{
    const float* x  = (const float*)d_in[0];
    const float* wq = (const float*)d_in[1];
    const float* bq = (const float*)d_in[2];
    const float* wk = (const float*)d_in[3];
    const float* bk = (const float*)d_in[4];
    const float* wv = (const float*)d_in[5];
    const float* bv = (const float*)d_in[6];
    float* out = (float*)d_out;

    char* ws = (char*)d_ws;
    const size_t XH_BYTES = (size_t)M_TOK * CDIM * sizeof(_Float16);   // 51.4 MB
    const size_t WT_BYTES = (size_t)3 * CDIM * CDIM * sizeof(_Float16);
    _Float16* xh  = (_Float16*)ws;
    _Float16* wt  = (_Float16*)(ws + XH_BYTES);
    _Float16* qkv = (_Float16*)(ws + XH_BYTES + WT_BYTES);
    _Float16* qh = qkv;
    _Float16* kh = qkv + (size_t)M_TOK * CDIM;
    _Float16* vh = kh  + (size_t)M_TOK * CDIM;

    cvt_f32_f16<<<12544, 256, 0, stream>>>(x, xh);
    cvt_w_t<<<dim3(16, 16, 3), 256, 0, stream>>>(wq, wk, wv, wt);
    qkv_gemm_f16<<<dim3(CDIM / 128, M_TOK / 128, 3), 256, 0, stream>>>(
        xh, wt, bq, bk, bv, qkv);
    knorm_f16<<<M_TOK / 4, 256, 0, stream>>>(kh);
    local_attn_f16<<<NBATCH * NWIN, 448, 0, stream>>>(qh, kh, vh, out);
}